// Round 1
// baseline (188.028 us; speedup 1.0000x reference)
//
#include <hip/hip_runtime.h>
#include <stdint.h>

// S4Block: out = xln + FIR(Khat, xln) + D_re * cumsum(xln), xln = LN(x @ W^T + b)
// ws layout: [0, 64MB) y/xln fp32 ; [64MB, +128KB) Khat[32][1024] fp32
// requires ws_size >= 64MB + 128KB

typedef __attribute__((ext_vector_type(8))) short short8;   // 8 bf16 (4 VGPR) MFMA frag
typedef __attribute__((ext_vector_type(4))) short short4v;  // 8B LDS write
typedef __attribute__((ext_vector_type(4))) float f32x4;

#define L_SEQ 2048
#define DM    1024
#define TT    32     // FIR taps kept (|A|^32 ~ 1e-14, tail negligible)
#define MT    16     // channels per SSM block
#define TC    256    // timesteps per SSM chunk

__device__ __forceinline__ unsigned short f2bf(float f) {
  uint32_t u = __builtin_bit_cast(uint32_t, f);
  u += 0x7FFFu + ((u >> 16) & 1u);   // round-to-nearest-even
  return (unsigned short)(u >> 16);
}

// ---------------- K1: Khat[s][m] = Re( sum_n A^s * B_n * C[m,n] ) ----------------
__global__ void kgen(const float* __restrict__ A_re, const float* __restrict__ A_im,
                     const float* __restrict__ B_re, const float* __restrict__ B_im,
                     const float* __restrict__ C_re, const float* __restrict__ C_im,
                     float* __restrict__ Khat) {
  int s = blockIdx.x;
  int tid = threadIdx.x;
  __shared__ float Pr[64], Pi[64];
  if (tid < 64) {
    float ar = A_re[tid], ai = A_im[tid];
    float pr, pi;
    if (s == 0) { pr = 1.f; pi = 0.f; }
    else {
      float r2 = ar * ar + ai * ai;
      float rs = expf(0.5f * (float)s * logf(r2));   // |A|^s  (log(0) -> -inf -> 0, ok)
      float ang = (float)s * atan2f(ai, ar);
      pr = rs * cosf(ang); pi = rs * sinf(ang);
    }
    float br = B_re[tid], bi = B_im[tid];
    Pr[tid] = pr * br - pi * bi;
    Pi[tid] = pr * bi + pi * br;
  }
  __syncthreads();
  for (int m = tid; m < DM; m += 256) {
    const float* cr = C_re + (size_t)m * 64;
    const float* ci = C_im + (size_t)m * 64;
    float acc = 0.f;
    #pragma unroll
    for (int n = 0; n < 64; ++n) acc += Pr[n] * cr[n] - Pi[n] * ci[n];
    Khat[(size_t)s * DM + m] = acc;
  }
}

// ---------------- K2: bf16 MFMA GEMM  Y[r,c] = sum_k X[r,k] W[c,k] + bias[c] -----
// 128x128 tile, BK=64, 4 waves (2x2), 4x4 frags of 16x16x32.
// fp32 global loads -> convert bf16 -> XOR-swizzled LDS (slot ^= row&7, 16B slots).
__global__ __launch_bounds__(256) void gemm_bias(const float* __restrict__ X,
                                                 const float* __restrict__ W,
                                                 const float* __restrict__ bias,
                                                 float* __restrict__ Y) {
  __shared__ short As[128 * 64];
  __shared__ short Bs[128 * 64];
  int wg = blockIdx.x;                       // 1024 blocks; 1024 % 8 == 0 -> simple XCD swizzle
  int swz = (wg & 7) * 128 + (wg >> 3);
  int bm = swz >> 3, bn = swz & 7;
  int tid = threadIdx.x;
  int lane = tid & 63, wid = tid >> 6;
  int wr = wid >> 1, wc = wid & 1;

  f32x4 acc[4][4];
  #pragma unroll
  for (int i = 0; i < 4; ++i)
    #pragma unroll
    for (int j = 0; j < 4; ++j) acc[i][j] = (f32x4){0.f, 0.f, 0.f, 0.f};

  int lrow = tid >> 4;              // staging: 16 rows/iter, 16 lanes cover 64 k
  int lk4 = (tid & 15) << 2;        // fp32 k offset
  int slot = lk4 >> 3;              // 16B slot within row
  int half = (lk4 >> 2) & 1;        // 8B half of slot
  const float* xb = X + (size_t)bm * 128 * DM;
  const float* wb = W + (size_t)bn * 128 * DM;

  for (int k0 = 0; k0 < DM; k0 += 64) {
    f32x4 av[8], bv[8];
    #pragma unroll
    for (int j = 0; j < 8; ++j) {
      int row = j * 16 + lrow;
      av[j] = *(const f32x4*)(xb + (size_t)row * DM + k0 + lk4);
      bv[j] = *(const f32x4*)(wb + (size_t)row * DM + k0 + lk4);
    }
    #pragma unroll
    for (int j = 0; j < 8; ++j) {
      int row = j * 16 + lrow;
      int off = row * 128 + ((slot ^ (row & 7)) << 4) + half * 8;
      short4v a4, b4;
      #pragma unroll
      for (int e = 0; e < 4; ++e) {
        a4[e] = (short)f2bf(av[j][e]);
        b4[e] = (short)f2bf(bv[j][e]);
      }
      *(short4v*)((char*)As + off) = a4;
      *(short4v*)((char*)Bs + off) = b4;
    }
    __syncthreads();
    {
      int fr = lane & 15, kg = lane >> 4;
      #pragma unroll
      for (int h = 0; h < 2; ++h) {
        short8 af[4], bf8[4];
        #pragma unroll
        for (int mi = 0; mi < 4; ++mi) {
          int row = wr * 64 + mi * 16 + fr;
          int sl = h * 4 + kg;
          af[mi] = *(const short8*)((const char*)As + row * 128 + ((sl ^ (row & 7)) << 4));
        }
        #pragma unroll
        for (int ni = 0; ni < 4; ++ni) {
          int row = wc * 64 + ni * 16 + fr;
          int sl = h * 4 + kg;
          bf8[ni] = *(const short8*)((const char*)Bs + row * 128 + ((sl ^ (row & 7)) << 4));
        }
        #pragma unroll
        for (int mi = 0; mi < 4; ++mi)
          #pragma unroll
          for (int ni = 0; ni < 4; ++ni)
            acc[mi][ni] = __builtin_amdgcn_mfma_f32_16x16x32_bf16(af[mi], bf8[ni], acc[mi][ni], 0, 0, 0);
      }
    }
    __syncthreads();
  }
  // epilogue: C/D layout col = lane&15, row = (lane>>4)*4 + j  [m89-verified]
  int fr = lane & 15, fq = lane >> 4;
  #pragma unroll
  for (int ni = 0; ni < 4; ++ni) {
    int col = bn * 128 + wc * 64 + ni * 16 + fr;
    float bvv = bias[col];
    #pragma unroll
    for (int mi = 0; mi < 4; ++mi) {
      int row = bm * 128 + wr * 64 + mi * 16 + fq * 4;
      #pragma unroll
      for (int j = 0; j < 4; ++j)
        Y[(size_t)(row + j) * DM + col] = acc[mi][ni][j] + bvv;
    }
  }
}

// ---------------- K3: LayerNorm in-place over last dim (1024) --------------------
__global__ __launch_bounds__(256) void ln_kernel(float* __restrict__ Y,
                                                 const float* __restrict__ gamma,
                                                 const float* __restrict__ beta) {
  size_t row = blockIdx.x;
  float* p = Y + row * DM;
  int tid = threadIdx.x;
  f32x4 v = *(f32x4*)(p + tid * 4);
  float s = v[0] + v[1] + v[2] + v[3];
  float s2 = v[0] * v[0] + v[1] * v[1] + v[2] * v[2] + v[3] * v[3];
  #pragma unroll
  for (int d = 32; d >= 1; d >>= 1) {
    s += __shfl_xor(s, d);
    s2 += __shfl_xor(s2, d);
  }
  __shared__ float red[8];
  int lane = tid & 63, wid = tid >> 6;
  if (lane == 0) { red[wid] = s; red[4 + wid] = s2; }
  __syncthreads();
  s = red[0] + red[1] + red[2] + red[3];
  s2 = red[4] + red[5] + red[6] + red[7];
  float mu = s * (1.f / DM);
  float var = s2 * (1.f / DM) - mu * mu;
  float inv = rsqrtf(var + 1e-5f);
  f32x4 g = *(const f32x4*)(gamma + tid * 4);
  f32x4 be = *(const f32x4*)(beta + tid * 4);
  f32x4 o;
  #pragma unroll
  for (int e = 0; e < 4; ++e) o[e] = (v[e] - mu) * inv * g[e] + be[e];
  *(f32x4*)(p + tid * 4) = o;
}

// ---------------- K4: out = xln + FIR(Khat) + D_re * cumsum(xln) -----------------
// block = (b, 16-channel tile); sequential 256-step chunks; shuffle-scan cumsum.
__global__ __launch_bounds__(256) void ssm_kernel(const float* __restrict__ Xln,
                                                  const float* __restrict__ Khat,
                                                  const float* __restrict__ D_re,
                                                  float* __restrict__ Out) {
  __shared__ float xs[TC + TT][MT + 1];   // +1 pad
  __shared__ float cum[TC][MT + 1];
  __shared__ float kh[TT][MT];
  int blk = blockIdx.x;
  int b = blk >> 6;                  // 64 m-tiles per batch
  int m0 = (blk & 63) * MT;
  int tid = threadIdx.x;
  int lm = tid & 15, lr = tid >> 4;  // load/store roles (coalesced)
  int m_ = tid >> 4, tg = tid & 15;  // compute roles (channel lanes contiguous)

  for (int j = tid; j < TT * MT; j += 256)
    kh[j >> 4][j & 15] = Khat[(size_t)(j >> 4) * DM + m0 + (j & 15)];
  float dre = D_re[m0 + m_];
  float carry = 0.f;

  for (int c = 0; c < L_SEQ / TC; ++c) {
    int cs = c * TC;
    // phase 1: load x tile (+TT halo; zeros before t=0)
    #pragma unroll
    for (int j = 0; j < (TC + TT) / 16; ++j) {
      int r = j * 16 + lr;
      int t = cs - TT + r;
      xs[r][lm] = (t >= 0) ? Xln[((size_t)(b * L_SEQ + t)) * DM + m0 + lm] : 0.f;
    }
    __syncthreads();
    // phase 2: cumsum (local serial sum + 16-lane shuffle scan + apply)
    float sl = 0.f;
    #pragma unroll
    for (int i = 0; i < 16; ++i) sl += xs[TT + tg * 16 + i][m_];
    float inc = sl;
    #pragma unroll
    for (int d = 1; d < 16; d <<= 1) {
      float o = __shfl_up(inc, d, 16);
      if (tg >= d) inc += o;
    }
    float run = carry + inc - sl;     // exclusive prefix + carry
    #pragma unroll
    for (int i = 0; i < 16; ++i) {
      run += xs[TT + tg * 16 + i][m_];
      cum[tg * 16 + i][m_] = run;
    }
    carry += __shfl(inc, 15, 16);     // chunk total
    __syncthreads();
    // phase 3: FIR + residual + D*cumsum (strided t -> conflict-free LDS reads)
    float res[16];
    #pragma unroll
    for (int i = 0; i < 16; ++i) {
      int tl = tg + 16 * i;
      float acc = 0.f;
      #pragma unroll
      for (int s = 0; s < TT; ++s) acc += kh[s][m_] * xs[TT + tl - s][m_];
      res[i] = xs[TT + tl][m_] + acc + dre * cum[tl][m_];
    }
    __syncthreads();
    #pragma unroll
    for (int i = 0; i < 16; ++i) cum[tg + 16 * i][m_] = res[i];   // own slots
    __syncthreads();
    // phase 4: coalesced store
    #pragma unroll
    for (int j = 0; j < TC / 16; ++j) {
      int r = j * 16 + lr;
      Out[((size_t)(b * L_SEQ + cs + r)) * DM + m0 + lm] = cum[r][lm];
    }
    __syncthreads();
  }
}

extern "C" void kernel_launch(void* const* d_in, const int* in_sizes, int n_in,
                              void* d_out, int out_size, void* d_ws, size_t ws_size,
                              hipStream_t stream) {
  const float* x     = (const float*)d_in[0];
  const float* W     = (const float*)d_in[1];
  const float* b_in  = (const float*)d_in[2];
  const float* gamma = (const float*)d_in[3];
  const float* beta  = (const float*)d_in[4];
  const float* A_re  = (const float*)d_in[5];
  const float* A_im  = (const float*)d_in[6];
  const float* B_re  = (const float*)d_in[7];
  const float* B_im  = (const float*)d_in[8];
  const float* C_re  = (const float*)d_in[9];
  const float* C_im  = (const float*)d_in[10];
  const float* D_re  = (const float*)d_in[11];
  // d_in[12] = D_im: only Re(conv) is kept by the reference -> D_im never affects out
  float* out  = (float*)d_out;
  float* y    = (float*)d_ws;                          // 8*2048*1024 fp32 (64MB)
  float* khat = y + (size_t)8 * L_SEQ * DM;            // 32*1024 fp32

  kgen<<<TT, 256, 0, stream>>>(A_re, A_im, B_re, B_im, C_re, C_im, khat);
  gemm_bias<<<1024, 256, 0, stream>>>(x, W, b_in, y);
  ln_kernel<<<8 * L_SEQ, 256, 0, stream>>>(y, gamma, beta);
  ssm_kernel<<<512, 256, 0, stream>>>(y, khat, D_re, out);
}